// Round 1
// 1254.826 us; speedup vs baseline: 1.0208x; 1.0208x over previous
//
#include <hip/hip_runtime.h>
#include <hip/hip_bf16.h>
#include <cstdint>
#include <cstddef>

typedef __attribute__((ext_vector_type(4))) float floatx4;
typedef __attribute__((ext_vector_type(8))) short shortx8;
typedef __attribute__((ext_vector_type(2))) __fp16 f16x2;

#define T_SEQ 512
#define NIN   512
#define BATCH 256
#define HID   256
#define G3    768
#define NC    101

static __device__ __forceinline__ unsigned short f2bf(float f){
  unsigned int u = __float_as_uint(f);
  u += 0x7FFFu + ((u >> 16) & 1u);
  return (unsigned short)(u >> 16);
}

static __device__ __forceinline__ float dot2acc(f16x2 w, f16x2 h, float acc){
#if __has_builtin(__builtin_amdgcn_fdot2)
  return __builtin_amdgcn_fdot2(w, h, acc, false);
#else
  return acc + (float)w[0]*(float)h[0] + (float)w[1]*(float)h[1];
#endif
}

// quad-lane butterfly add via DPP (VALU pipe, no LDS). 0xB1 = xor1, 0x4E = xor2.
template<int CTRL>
static __device__ __forceinline__ float dppadd(float v){
  return v + __int_as_float(__builtin_amdgcn_update_dpp(
      0, __float_as_int(v), CTRL, 0xF, 0xF, true));
}

// ---------------- Phase A: xg[b*Tc+tt][n] = x[b, t0+tt, :] . Wih[n, :] + bih[n]
#define BM 128
#define BN 128
#define BK 64
#define LDK 72

__global__ __launch_bounds__(256) void gemm_xg(
    const float* __restrict__ x, const float* __restrict__ Wih,
    const float* __restrict__ bih, float* __restrict__ xg,
    int t0, int tcLog2)
{
  __shared__ unsigned short As[BM*LDK];
  __shared__ unsigned short Bs[BN*LDK];
  const int tid  = threadIdx.x;
  const int bn   = blockIdx.x;   // N fastest: 6 consecutive blocks share one x-tile (L2 reuse)
  const int bm   = blockIdx.y;
  const int w    = tid >> 6;
  const int l    = tid & 63;
  const int lm   = l & 15;
  const int quad = l >> 4;

  const int srow = tid >> 4;
  const int scol = (tid & 15) * 4;
  const int tcMask = (1 << tcLog2) - 1;

  floatx4 acc[2][8];
  #pragma unroll
  for (int mt = 0; mt < 2; ++mt)
    #pragma unroll
    for (int nt = 0; nt < 8; ++nt)
      acc[mt][nt] = (floatx4){0.f, 0.f, 0.f, 0.f};

  for (int kt = 0; kt < NIN / BK; ++kt){
    const int k0 = kt * BK;
    __syncthreads();
    #pragma unroll
    for (int p = 0; p < 8; ++p){
      const int r  = p * 16 + srow;
      const int gm = bm * BM + r;
      const int b  = gm >> tcLog2;
      const int tt = gm & tcMask;
      const float4 xa = *(const float4*)(x + (size_t)(b * T_SEQ + t0 + tt) * NIN + k0 + scol);
      union { unsigned short u[4]; uint2 v; } pa;
      pa.u[0] = f2bf(xa.x); pa.u[1] = f2bf(xa.y); pa.u[2] = f2bf(xa.z); pa.u[3] = f2bf(xa.w);
      *(uint2*)&As[r * LDK + scol] = pa.v;
      const int gn = bn * BN + r;
      const float4 wb = *(const float4*)(Wih + (size_t)gn * NIN + k0 + scol);
      union { unsigned short u[4]; uint2 v; } pb;
      pb.u[0] = f2bf(wb.x); pb.u[1] = f2bf(wb.y); pb.u[2] = f2bf(wb.z); pb.u[3] = f2bf(wb.w);
      *(uint2*)&Bs[r * LDK + scol] = pb.v;
    }
    __syncthreads();
    #pragma unroll
    for (int ks = 0; ks < 2; ++ks){
      const int kk = ks * 32 + quad * 8;
      shortx8 af[2], bfr[8];
      #pragma unroll
      for (int mt = 0; mt < 2; ++mt)
        af[mt] = *(const shortx8*)&As[(w * 32 + mt * 16 + lm) * LDK + kk];
      #pragma unroll
      for (int nt = 0; nt < 8; ++nt)
        bfr[nt] = *(const shortx8*)&Bs[(nt * 16 + lm) * LDK + kk];
      #pragma unroll
      for (int mt = 0; mt < 2; ++mt)
        #pragma unroll
        for (int nt = 0; nt < 8; ++nt)
          acc[mt][nt] = __builtin_amdgcn_mfma_f32_16x16x32_bf16(af[mt], bfr[nt], acc[mt][nt], 0, 0, 0);
    }
  }

  #pragma unroll
  for (int mt = 0; mt < 2; ++mt){
    #pragma unroll
    for (int nt = 0; nt < 8; ++nt){
      #pragma unroll
      for (int i = 0; i < 4; ++i){
        const int ml = w * 32 + mt * 16 + quad * 4 + i;
        const int nl = nt * 16 + lm;
        const int gm = bm * BM + ml;
        const int gn = bn * BN + nl;
        xg[(size_t)gm * G3 + gn] = acc[mt][nt][i] + bih[gn];
      }
    }
  }
}

// ---------------- Phase B: sequential GRU, g=2 restructure.
// tid = 4*g + q: group g handles j0=g and j1=g+128; lane q covers h[64q..64q+64).
// Each thread: 192 fdot2 (6 accumulator chains), only 8 ds_read_b128 per step
// (halves LDS broadcast traffic vs the old half-split). Quarter reduction via
// DPP quad_perm butterfly (VALU pipe, no ds_swizzle). h stored f16 with +16 B
// pad per 64 elems: the wave's 4 distinct read addresses hit disjoint 4-bank
// groups (stride 144 B -> banks {0-3},{4-7},{8-11},{12-15}).
#define HSTRIDE 280   // u16 per buffer: pos(k) = k + 8*(k>>6); 280*2 = 560 B (16B-aligned)

__global__ __launch_bounds__(512, 2) void gru_steps(
    const float* __restrict__ xg, const float* __restrict__ Whh,
    const float* __restrict__ bhh, float* __restrict__ hstate, int Tc)
{
  __shared__ alignas(16) unsigned short hph[2][HSTRIDE];
  const int b   = blockIdx.x;
  const int tid = threadIdx.x;
  const int q   = tid & 3;          // K-quarter
  const int g   = tid >> 2;         // 0..127: j-pair group
  const int sel = q >> 1;           // 0 -> j0=g, 1 -> j1=g+128
  const int jm  = g + (sel << 7);   // this lane's j for xg / act / h tracking
  const int k0  = q << 6;           // h-element base of this lane's K-quarter

  // Weights: 6 row-slices x 64 cols f16 = 192 f16x2 VGPRs (W_hh resident once per block)
  f16x2 w0r[32], w0z[32], w0n[32], w1r[32], w1z[32], w1n[32];
  {
    const float4* p0 = (const float4*)(Whh + (size_t)(g      ) * HID + k0);
    #pragma unroll
    for (int k = 0; k < 16; ++k){ float4 v = p0[k];
      w0r[2*k] = __builtin_amdgcn_cvt_pkrtz(v.x, v.y); w0r[2*k+1] = __builtin_amdgcn_cvt_pkrtz(v.z, v.w); }
    const float4* p1 = (const float4*)(Whh + (size_t)(g + 256) * HID + k0);
    #pragma unroll
    for (int k = 0; k < 16; ++k){ float4 v = p1[k];
      w0z[2*k] = __builtin_amdgcn_cvt_pkrtz(v.x, v.y); w0z[2*k+1] = __builtin_amdgcn_cvt_pkrtz(v.z, v.w); }
    const float4* p2 = (const float4*)(Whh + (size_t)(g + 512) * HID + k0);
    #pragma unroll
    for (int k = 0; k < 16; ++k){ float4 v = p2[k];
      w0n[2*k] = __builtin_amdgcn_cvt_pkrtz(v.x, v.y); w0n[2*k+1] = __builtin_amdgcn_cvt_pkrtz(v.z, v.w); }
    const float4* p3 = (const float4*)(Whh + (size_t)(g + 128) * HID + k0);
    #pragma unroll
    for (int k = 0; k < 16; ++k){ float4 v = p3[k];
      w1r[2*k] = __builtin_amdgcn_cvt_pkrtz(v.x, v.y); w1r[2*k+1] = __builtin_amdgcn_cvt_pkrtz(v.z, v.w); }
    const float4* p4 = (const float4*)(Whh + (size_t)(g + 384) * HID + k0);
    #pragma unroll
    for (int k = 0; k < 16; ++k){ float4 v = p4[k];
      w1z[2*k] = __builtin_amdgcn_cvt_pkrtz(v.x, v.y); w1z[2*k+1] = __builtin_amdgcn_cvt_pkrtz(v.z, v.w); }
    const float4* p5 = (const float4*)(Whh + (size_t)(g + 640) * HID + k0);
    #pragma unroll
    for (int k = 0; k < 16; ++k){ float4 v = p5[k];
      w1n[2*k] = __builtin_amdgcn_cvt_pkrtz(v.x, v.y); w1n[2*k+1] = __builtin_amdgcn_cvt_pkrtz(v.z, v.w); }
  }
  const float br = bhh[jm];
  const float bz = bhh[jm + 256];
  const float bn = bhh[jm + 512];

  float hj = hstate[b * HID + jm];
  const int wpos = jm + ((jm >> 6) << 3);   // padded u16 position of jm
  if (!(q & 1)){
    union { __fp16 f; unsigned short u; } cv;
    cv.f = (__fp16)hj;
    hph[0][wpos] = cv.u;
  }
  __syncthreads();

  const int xbase = b * Tc * G3 + jm;       // fits in int (max ~100.6M)
  float xr = xg[xbase], xz = xg[xbase + 256], xn = xg[xbase + 512];

  #pragma unroll 1
  for (int t = 0; t < Tc; ++t){
    const int tn = (t + 1 < Tc) ? (t + 1) : t;
    const int xo = xbase + tn * G3;
    const float nxr = xg[xo];
    const float nxz = xg[xo + 256];
    const float nxn = xg[xo + 512];

    // This lane's 64 h-elems: 8 x b128 at byte 144*q + 16*i (conflict-free, broadcast x16)
    const uint4* hp4 = (const uint4*)(&hph[t & 1][0]) + 9 * q;
    uint4 hv[8];
    #pragma unroll
    for (int i = 0; i < 8; ++i) hv[i] = hp4[i];

    float a0r = 0.f, a0z = 0.f, a0n = 0.f, a1r = 0.f, a1z = 0.f, a1n = 0.f;
    #pragma unroll
    for (int i = 0; i < 8; ++i){
      union { unsigned int u; f16x2 h; } c0, c1, c2, c3;
      c0.u = hv[i].x; c1.u = hv[i].y; c2.u = hv[i].z; c3.u = hv[i].w;
      const int p = 4 * i;
      a0r = dot2acc(w0r[p    ], c0.h, a0r);
      a0z = dot2acc(w0z[p    ], c0.h, a0z);
      a0n = dot2acc(w0n[p    ], c0.h, a0n);
      a1r = dot2acc(w1r[p    ], c0.h, a1r);
      a1z = dot2acc(w1z[p    ], c0.h, a1z);
      a1n = dot2acc(w1n[p    ], c0.h, a1n);
      a0r = dot2acc(w0r[p + 1], c1.h, a0r);
      a0z = dot2acc(w0z[p + 1], c1.h, a0z);
      a0n = dot2acc(w0n[p + 1], c1.h, a0n);
      a1r = dot2acc(w1r[p + 1], c1.h, a1r);
      a1z = dot2acc(w1z[p + 1], c1.h, a1z);
      a1n = dot2acc(w1n[p + 1], c1.h, a1n);
      a0r = dot2acc(w0r[p + 2], c2.h, a0r);
      a0z = dot2acc(w0z[p + 2], c2.h, a0z);
      a0n = dot2acc(w0n[p + 2], c2.h, a0n);
      a1r = dot2acc(w1r[p + 2], c2.h, a1r);
      a1z = dot2acc(w1z[p + 2], c2.h, a1z);
      a1n = dot2acc(w1n[p + 2], c2.h, a1n);
      a0r = dot2acc(w0r[p + 3], c3.h, a0r);
      a0z = dot2acc(w0z[p + 3], c3.h, a0z);
      a0n = dot2acc(w0n[p + 3], c3.h, a0n);
      a1r = dot2acc(w1r[p + 3], c3.h, a1r);
      a1z = dot2acc(w1z[p + 3], c3.h, a1z);
      a1n = dot2acc(w1n[p + 3], c3.h, a1n);
    }

    // quad butterfly: all 4 lanes of the group end with full 256-elem sums
    a0r = dppadd<0xB1>(a0r); a0z = dppadd<0xB1>(a0z); a0n = dppadd<0xB1>(a0n);
    a1r = dppadd<0xB1>(a1r); a1z = dppadd<0xB1>(a1z); a1n = dppadd<0xB1>(a1n);
    a0r = dppadd<0x4E>(a0r); a0z = dppadd<0x4E>(a0z); a0n = dppadd<0x4E>(a0n);
    a1r = dppadd<0x4E>(a1r); a1z = dppadd<0x4E>(a1z); a1n = dppadd<0x4E>(a1n);

    const float hr = (sel ? a1r : a0r) + br;
    const float hz = (sel ? a1z : a0z) + bz;
    const float hn = (sel ? a1n : a0n) + bn;

    const float r = 1.f / (1.f + __expf(-(xr + hr)));
    const float z = 1.f / (1.f + __expf(-(xz + hz)));
    const float a = xn + r * hn;
    const float ex = __expf(-2.f * fabsf(a));
    float n = (1.f - ex) / (1.f + ex);
    n = copysignf(n, a);
    const float hnew = fmaf(z, hj - n, n);   // (1-z)*n + z*h

    hj = hnew;
    if (!(q & 1)){
      union { __fp16 f; unsigned short u; } cv;
      cv.f = (__fp16)hj;
      hph[1 - (t & 1)][wpos] = cv.u;   // write other buffer: no race with reads
    }
    __syncthreads();                    // single barrier: new buffer visible
    xr = nxr; xz = nxz; xn = nxn;
  }

  if (!(q & 1)) hstate[b * HID + jm] = hj;
}

// ---------------- FC
__global__ __launch_bounds__(128) void fc_kernel(
    const float* __restrict__ hstate, const float* __restrict__ fw,
    const float* __restrict__ fb, float* __restrict__ out)
{
  __shared__ float hs[HID];
  const int b = blockIdx.x;
  const int t = threadIdx.x;
  hs[t]       = hstate[b * HID + t];
  hs[t + 128] = hstate[b * HID + t + 128];
  __syncthreads();
  if (t < NC){
    float acc = fb[t];
    const float4* w4 = (const float4*)(fw + (size_t)t * HID);
    const float4* h4 = (const float4*)hs;
    #pragma unroll
    for (int k = 0; k < 64; ++k){
      const float4 wv = w4[k];
      const float4 hv = h4[k];
      acc += wv.x * hv.x + wv.y * hv.y + wv.z * hv.z + wv.w * hv.w;
    }
    out[b * NC + t] = acc;
  }
}

extern "C" void kernel_launch(void* const* d_in, const int* in_sizes, int n_in,
                              void* d_out, int out_size, void* d_ws, size_t ws_size,
                              hipStream_t stream)
{
  const float* x   = (const float*)d_in[0];
  const float* Wih = (const float*)d_in[1];
  const float* Whh = (const float*)d_in[2];
  const float* bih = (const float*)d_in[3];
  const float* bhh = (const float*)d_in[4];
  const float* fcw = (const float*)d_in[5];
  const float* fcb = (const float*)d_in[6];
  float* out = (float*)d_out;

  float* hst = (float*)d_ws;
  const size_t hBytes = (size_t)BATCH * HID * sizeof(float);
  float* xg  = (float*)((char*)d_ws + hBytes);

  const size_t perT = (size_t)BATCH * G3 * sizeof(float);
  const size_t avail = (ws_size > hBytes) ? (ws_size - hBytes) : 0;
  int tcLog2 = 9;
  while (tcLog2 > 0 && perT * ((size_t)1 << tcLog2) > avail) --tcLog2;
  const int Tc = 1 << tcLog2;

  (void)hipMemsetAsync(hst, 0, hBytes, stream);
  for (int t0 = 0; t0 < T_SEQ; t0 += Tc){
    dim3 grid(6, 2 * Tc);
    gemm_xg<<<grid, 256, 0, stream>>>(x, Wih, bih, xg, t0, tcLog2);
    gru_steps<<<BATCH, 512, 0, stream>>>(xg, Whh, bhh, hst, Tc);
  }
  fc_kernel<<<BATCH, 128, 0, stream>>>(hst, fcw, fcb, out);
}